// Round 1
// baseline (96.894 us; speedup 1.0000x reference)
//
#include <hip/hip_runtime.h>
#include <hip/hip_bf16.h>

// ---- problem constants ----
#define B_IMG   128
#define CH      3
#define HW      224
#define NPATCH  196          // tokens per image
#define TOKENS  25088        // B_IMG * NPATCH
#define PATCH   16
#define FDIM    768          // C*P*P (K of the GEMM)
#define DDIM    768          // output embed dim (N of the GEMM)
#define TOKELEMS ((size_t)TOKENS * FDIM)       // patch matrix elements
#define OUT_TOKENS ((size_t)TOKENS * DDIM)     // 19267584 floats, positions follow

typedef short short8 __attribute__((ext_vector_type(8)));
typedef float f32x4  __attribute__((ext_vector_type(4)));

static __device__ __forceinline__ unsigned short f2bf(float v) {
  // round-to-nearest-even f32 -> bf16 (inputs are finite)
  unsigned u = __float_as_uint(v);
  unsigned r = u + 0x7fffu + ((u >> 16) & 1u);
  return (unsigned short)(r >> 16);
}

static __device__ __forceinline__ void gload16(const short* g, short* l) {
  __builtin_amdgcn_global_load_lds(
      (const __attribute__((address_space(1))) void*)g,
      (__attribute__((address_space(3))) void*)l,
      16, 0, 0);
}

// ---- kernel 1: W_proj f32 -> bf16 ----
__global__ __launch_bounds__(256) void convert_w_kernel(
    const float* __restrict__ W, short* __restrict__ Wbf) {
  int i = (blockIdx.x * 256 + threadIdx.x) * 4;   // 589824 total elems, exact grid
  float4 v = *(const float4*)&W[i];
  ushort4 o;
  o.x = f2bf(v.x); o.y = f2bf(v.y); o.z = f2bf(v.z); o.w = f2bf(v.w);
  *(ushort4*)&Wbf[i] = o;
}

// ---- kernel 2: gather patches -> bf16 matrix [TOKENS][768], + positions ----
__global__ __launch_bounds__(256) void gather_kernel(
    const float* __restrict__ x, const int* __restrict__ ys,
    const int* __restrict__ xs, short* __restrict__ patches,
    float* __restrict__ pos) {
  int e   = blockIdx.x * 256 + threadIdx.x;  // quad index; grid exact (TOKENS*192)
  int tok = e / 192;
  int q   = e - tok * 192;
  int f   = q * 4;
  int b   = tok / NPATCH;
  int y   = ys[tok];
  int xc  = xs[tok];
  int c   = f >> 8;            // f / 256
  int rem = f & 255;
  int py  = rem >> 4;
  int px  = rem & 15;
  const float* src = x + ((size_t)(b * CH + c) * HW + (y + py)) * HW + xc + px;
  ushort4 o;
  o.x = f2bf(src[0]); o.y = f2bf(src[1]); o.z = f2bf(src[2]); o.w = f2bf(src[3]);
  *(ushort4*)&patches[(size_t)tok * FDIM + f] = o;
  if (q == 0) {
    pos[(size_t)tok * 2]     = (float)y;
    pos[(size_t)tok * 2 + 1] = (float)xc;
  }
}

// ---- kernel 3: bf16 MFMA GEMM, m97 structure ----
// C[m][d] = sum_f A[m][f] * Wbf[d][f] + bias[d]
// tile 128x128, BK=32, 4 waves (2x2), each wave 64x64 = 4x4 x (16x16x32) frags
__global__ __launch_bounds__(256) void gemm_kernel(
    const short* __restrict__ A,    // patches bf16 [TOKENS][768]
    const short* __restrict__ Bw,   // Wbf bf16 [768][768]
    const float* __restrict__ bias,
    float* __restrict__ C) {
  __shared__ short At[128 * 32];
  __shared__ short Bt[128 * 32];

  const int tid  = threadIdx.x;
  const int w    = tid >> 6;
  const int l    = tid & 63;
  const int m0   = blockIdx.y * 128;
  const int n0   = blockIdx.x * 128;
  const int wrow = w >> 1;
  const int wcol = w & 1;
  const int lr   = l & 15;
  const int lg   = l >> 4;

  f32x4 acc[4][4];
  const f32x4 z = {0.f, 0.f, 0.f, 0.f};
#pragma unroll
  for (int mi = 0; mi < 4; ++mi)
#pragma unroll
    for (int ni = 0; ni < 4; ++ni) acc[mi][ni] = z;

  // staging: each wave stages 32 rows (2 chunks of 16 rows) per operand.
  // one global_load_lds: 64 lanes x 16B = 1024B = 16 rows of 64B; lane l ->
  // row l>>2, in-row bf16 offset (l&3)*8. LDS dest base is wave-uniform.
  const int rw = w * 32;
  const short* gA = A + (size_t)(m0 + rw + (l >> 2)) * FDIM + ((l & 3) << 3);
  const short* gB = Bw + (size_t)(n0 + rw + (l >> 2)) * FDIM + ((l & 3) << 3);
  short* lA = At + rw * 32;
  short* lB = Bt + rw * 32;

  for (int kt = 0; kt < 24; ++kt) {
    const int ko = kt * 32;
    gload16(gA + ko, lA);
    gload16(gA + 16 * FDIM + ko, lA + 16 * 32);
    gload16(gB + ko, lB);
    gload16(gB + 16 * FDIM + ko, lB + 16 * 32);
    asm volatile("s_waitcnt vmcnt(0)" ::: "memory");
    __syncthreads();

    short8 a[4], b[4];
    const int koff = lg * 8;
#pragma unroll
    for (int mi = 0; mi < 4; ++mi)
      a[mi] = *(const short8*)&At[(wrow * 64 + mi * 16 + lr) * 32 + koff];
#pragma unroll
    for (int ni = 0; ni < 4; ++ni)
      b[ni] = *(const short8*)&Bt[(wcol * 64 + ni * 16 + lr) * 32 + koff];
#pragma unroll
    for (int mi = 0; mi < 4; ++mi)
#pragma unroll
      for (int ni = 0; ni < 4; ++ni)
        acc[mi][ni] =
            __builtin_amdgcn_mfma_f32_16x16x32_bf16(a[mi], b[ni], acc[mi][ni], 0, 0, 0);
    __syncthreads();
  }

  // epilogue: C/D layout col = lane&15, row = (lane>>4)*4 + j
#pragma unroll
  for (int ni = 0; ni < 4; ++ni) {
    const int col = n0 + wcol * 64 + ni * 16 + lr;
    const float bs = bias[col];
#pragma unroll
    for (int mi = 0; mi < 4; ++mi) {
      const int row = m0 + wrow * 64 + mi * 16 + lg * 4;
      const f32x4 v = acc[mi][ni];
#pragma unroll
      for (int j = 0; j < 4; ++j)
        C[(size_t)(row + j) * DDIM + col] = v[j] + bs;
    }
  }
}

// ---- fallback (ws too small): naive fused f32, correct but slow ----
__global__ __launch_bounds__(256) void naive_kernel(
    const float* __restrict__ x, const int* __restrict__ ys,
    const int* __restrict__ xs, const float* __restrict__ W,
    const float* __restrict__ bias, float* __restrict__ out) {
  __shared__ float prow[FDIM];
  const int tok = blockIdx.x;
  const int t   = threadIdx.x;
  const int b   = tok / NPATCH;
  const int y   = ys[tok];
  const int xc  = xs[tok];
  for (int i = t; i < FDIM; i += 256) {
    int c = i >> 8, rem = i & 255, py = rem >> 4, px = rem & 15;
    prow[i] = x[((size_t)(b * CH + c) * HW + y + py) * HW + xc + px];
  }
  __syncthreads();
  for (int dd = 0; dd < 3; ++dd) {
    const int d = t + dd * 256;
    float s = bias[d];
    const float4* wr = (const float4*)&W[(size_t)d * FDIM];
    const float4* pr = (const float4*)prow;
    for (int f4 = 0; f4 < FDIM / 4; ++f4) {
      float4 wv = wr[f4];
      float4 pv = pr[f4];
      s += wv.x * pv.x + wv.y * pv.y + wv.z * pv.z + wv.w * pv.w;
    }
    out[(size_t)tok * DDIM + d] = s;
  }
  if (t == 0) {
    float* pos = out + OUT_TOKENS;
    pos[(size_t)tok * 2]     = (float)y;
    pos[(size_t)tok * 2 + 1] = (float)xc;
  }
}

extern "C" void kernel_launch(void* const* d_in, const int* in_sizes, int n_in,
                              void* d_out, int out_size, void* d_ws, size_t ws_size,
                              hipStream_t stream) {
  const float* x    = (const float*)d_in[0];
  const int*   ys   = (const int*)d_in[1];
  const int*   xs   = (const int*)d_in[2];
  const float* W    = (const float*)d_in[3];
  const float* bias = (const float*)d_in[4];
  float* out = (float*)d_out;
  float* pos = out + OUT_TOKENS;

  const size_t w_bytes = (size_t)DDIM * FDIM * 2;     // 1,179,648
  const size_t p_bytes = TOKELEMS * 2;                // 38,535,168
  if (ws_size >= w_bytes + p_bytes) {
    short* Wbf     = (short*)d_ws;
    short* patches = (short*)d_ws + (size_t)DDIM * FDIM;
    convert_w_kernel<<<(DDIM * FDIM / 4) / 256, 256, 0, stream>>>(W, Wbf);
    gather_kernel<<<(TOKENS * (FDIM / 4)) / 256, 256, 0, stream>>>(x, ys, xs, patches, pos);
    dim3 grid(DDIM / 128, TOKENS / 128);   // 6 x 196
    gemm_kernel<<<grid, 256, 0, stream>>>(patches, Wbf, bias, out);
  } else {
    naive_kernel<<<TOKENS, 256, 0, stream>>>(x, ys, xs, W, bias, out);
  }
}

// Round 2
// 93.013 us; speedup vs baseline: 1.0417x; 1.0417x over previous
//
#include <hip/hip_runtime.h>
#include <hip/hip_bf16.h>

// ---- problem constants ----
#define B_IMG   128
#define CH      3
#define HW      224
#define NPATCH  196          // tokens per image
#define TOKENS  25088        // B_IMG * NPATCH
#define PATCH   16
#define FDIM    768          // C*P*P (K of the GEMM)
#define DDIM    768          // output embed dim (N of the GEMM)
#define TOKELEMS ((size_t)TOKENS * FDIM)       // patch matrix elements
#define OUT_TOKENS ((size_t)TOKENS * DDIM)     // 19267584 floats, positions follow

#define GATHER_BLOCKS (TOKENS * (FDIM / 4) / 256)   // 18816
#define WCONV_BLOCKS  ((DDIM * FDIM / 4) / 256)     // 576

typedef short short8 __attribute__((ext_vector_type(8)));
typedef float f32x4  __attribute__((ext_vector_type(4)));

static __device__ __forceinline__ unsigned short f2bf(float v) {
  unsigned u = __float_as_uint(v);
  unsigned r = u + 0x7fffu + ((u >> 16) & 1u);
  return (unsigned short)(r >> 16);
}

static __device__ __forceinline__ void gload16(const short* g, short* l) {
  __builtin_amdgcn_global_load_lds(
      (const __attribute__((address_space(1))) void*)g,
      (__attribute__((address_space(3))) void*)l,
      16, 0, 0);
}

// ---- kernel 1: gather patches -> bf16 [TOKENS][768] + positions, and W -> bf16 ----
__global__ __launch_bounds__(256) void prep_kernel(
    const float* __restrict__ x, const int* __restrict__ ys,
    const int* __restrict__ xs, const float* __restrict__ W,
    short* __restrict__ patches, short* __restrict__ Wbf,
    float* __restrict__ pos) {
  const int blk = blockIdx.x;
  if (blk < GATHER_BLOCKS) {
    int e   = blk * 256 + threadIdx.x;      // quad index
    int tok = e / 192;
    int q   = e - tok * 192;
    int f   = q * 4;
    int b   = tok / NPATCH;
    int y   = ys[tok];
    int xc  = xs[tok];
    int c   = f >> 8;
    int rem = f & 255;
    int py  = rem >> 4;
    int px  = rem & 15;
    const float* src = x + ((size_t)(b * CH + c) * HW + (y + py)) * HW + xc + px;
    ushort4 o;
    o.x = f2bf(src[0]); o.y = f2bf(src[1]); o.z = f2bf(src[2]); o.w = f2bf(src[3]);
    *(ushort4*)&patches[(size_t)tok * FDIM + f] = o;
    if (q == 0) {
      pos[(size_t)tok * 2]     = (float)y;
      pos[(size_t)tok * 2 + 1] = (float)xc;
    }
  } else {
    int i = ((blk - GATHER_BLOCKS) * 256 + threadIdx.x) * 4;
    float4 v = *(const float4*)&W[i];
    ushort4 o;
    o.x = f2bf(v.x); o.y = f2bf(v.y); o.z = f2bf(v.z); o.w = f2bf(v.w);
    *(ushort4*)&Wbf[i] = o;
  }
}

// ---- kernel 2: bf16 MFMA GEMM, 128x128 tile, 2-phase double-buffered ----
// C[m][d] = sum_f A[m][f] * Wbf[d][f] + bias[d]
__global__ __launch_bounds__(256) void gemm_kernel(
    const short* __restrict__ A,    // patches bf16 [TOKENS][768]
    const short* __restrict__ Bw,   // Wbf bf16 [768][768]
    const float* __restrict__ bias,
    float* __restrict__ C) {
  __shared__ short At[2][128 * 32];
  __shared__ short Bt[2][128 * 32];

  const int tid  = threadIdx.x;
  const int w    = tid >> 6;
  const int l    = tid & 63;

  // bijective XCD swizzle: nwg = 1176 = 8 * 147. Groups the 6 N-tiles of
  // each M row-panel onto one XCD's L2 (A-panel fetched once, not 6x).
  const int id  = blockIdx.x;
  const int nid = (id & 7) * 147 + (id >> 3);
  const int m0  = (nid / 6) * 128;
  const int n0  = (nid % 6) * 128;

  const int wrow = w >> 1;
  const int wcol = w & 1;
  const int lr   = l & 15;
  const int lg   = l >> 4;

  f32x4 acc[4][4];
  const f32x4 z = {0.f, 0.f, 0.f, 0.f};
#pragma unroll
  for (int mi = 0; mi < 4; ++mi)
#pragma unroll
    for (int ni = 0; ni < 4; ++ni) acc[mi][ni] = z;

  // each wave stages 32 rows per operand (2 x global_load_lds of 16 rows)
  const int rw = w * 32;
  const short* gA = A + (size_t)(m0 + rw + (l >> 2)) * FDIM + ((l & 3) << 3);
  const short* gB = Bw + (size_t)(n0 + rw + (l >> 2)) * FDIM + ((l & 3) << 3);
  short* lA0 = &At[0][rw * 32];
  short* lA1 = &At[1][rw * 32];
  short* lB0 = &Bt[0][rw * 32];
  short* lB1 = &Bt[1][rw * 32];

  auto stage = [&](short* lA, short* lB, int ko) {
    gload16(gA + ko, lA);
    gload16(gA + 16 * FDIM + ko, lA + 16 * 32);
    gload16(gB + ko, lB);
    gload16(gB + 16 * FDIM + ko, lB + 16 * 32);
  };
  auto compute = [&](const short* Ab, const short* Bb) {
    short8 a[4], b[4];
    const int koff = lg * 8;
#pragma unroll
    for (int mi = 0; mi < 4; ++mi)
      a[mi] = *(const short8*)&Ab[(wrow * 64 + mi * 16 + lr) * 32 + koff];
#pragma unroll
    for (int ni = 0; ni < 4; ++ni)
      b[ni] = *(const short8*)&Bb[(wcol * 64 + ni * 16 + lr) * 32 + koff];
#pragma unroll
    for (int mi = 0; mi < 4; ++mi)
#pragma unroll
      for (int ni = 0; ni < 4; ++ni)
        acc[mi][ni] =
            __builtin_amdgcn_mfma_f32_16x16x32_bf16(a[mi], b[ni], acc[mi][ni], 0, 0, 0);
  };

  // prologue: stage K-tile 0 into buf0
  stage(lA0, lB0, 0);
  asm volatile("s_waitcnt vmcnt(0)" ::: "memory");
  __syncthreads();

  for (int kt = 0; kt < 24; kt += 2) {
    // stage kt+1 into buf1 BEFORE computing buf0 — latency hides under MFMA
    stage(lA1, lB1, (kt + 1) * 32);
    compute(At[0], Bt[0]);
    asm volatile("s_waitcnt vmcnt(0)" ::: "memory");
    __syncthreads();
    if (kt + 2 < 24) stage(lA0, lB0, (kt + 2) * 32);
    compute(At[1], Bt[1]);
    asm volatile("s_waitcnt vmcnt(0)" ::: "memory");
    __syncthreads();
  }

  // epilogue: C/D layout col = lane&15, row = (lane>>4)*4 + j
#pragma unroll
  for (int ni = 0; ni < 4; ++ni) {
    const int col = n0 + wcol * 64 + ni * 16 + lr;
    const float bs = bias[col];
#pragma unroll
    for (int mi = 0; mi < 4; ++mi) {
      const int row = m0 + wrow * 64 + mi * 16 + lg * 4;
      const f32x4 v = acc[mi][ni];
#pragma unroll
      for (int j = 0; j < 4; ++j)
        C[(size_t)(row + j) * DDIM + col] = v[j] + bs;
    }
  }
}

// ---- fallback (ws too small): naive fused f32, correct but slow ----
__global__ __launch_bounds__(256) void naive_kernel(
    const float* __restrict__ x, const int* __restrict__ ys,
    const int* __restrict__ xs, const float* __restrict__ W,
    const float* __restrict__ bias, float* __restrict__ out) {
  __shared__ float prow[FDIM];
  const int tok = blockIdx.x;
  const int t   = threadIdx.x;
  const int b   = tok / NPATCH;
  const int y   = ys[tok];
  const int xc  = xs[tok];
  for (int i = t; i < FDIM; i += 256) {
    int c = i >> 8, rem = i & 255, py = rem >> 4, px = rem & 15;
    prow[i] = x[((size_t)(b * CH + c) * HW + y + py) * HW + xc + px];
  }
  __syncthreads();
  for (int dd = 0; dd < 3; ++dd) {
    const int d = t + dd * 256;
    float s = bias[d];
    const float4* wr = (const float4*)&W[(size_t)d * FDIM];
    const float4* pr = (const float4*)prow;
    for (int f4 = 0; f4 < FDIM / 4; ++f4) {
      float4 wv = wr[f4];
      float4 pv = pr[f4];
      s += wv.x * pv.x + wv.y * pv.y + wv.z * pv.z + wv.w * pv.w;
    }
    out[(size_t)tok * DDIM + d] = s;
  }
  if (t == 0) {
    float* pos = out + OUT_TOKENS;
    pos[(size_t)tok * 2]     = (float)y;
    pos[(size_t)tok * 2 + 1] = (float)xc;
  }
}

extern "C" void kernel_launch(void* const* d_in, const int* in_sizes, int n_in,
                              void* d_out, int out_size, void* d_ws, size_t ws_size,
                              hipStream_t stream) {
  const float* x    = (const float*)d_in[0];
  const int*   ys   = (const int*)d_in[1];
  const int*   xs   = (const int*)d_in[2];
  const float* W    = (const float*)d_in[3];
  const float* bias = (const float*)d_in[4];
  float* out = (float*)d_out;
  float* pos = out + OUT_TOKENS;

  const size_t w_bytes = (size_t)DDIM * FDIM * 2;
  const size_t p_bytes = TOKELEMS * 2;
  if (ws_size >= w_bytes + p_bytes) {
    short* Wbf     = (short*)d_ws;
    short* patches = (short*)d_ws + (size_t)DDIM * FDIM;
    prep_kernel<<<GATHER_BLOCKS + WCONV_BLOCKS, 256, 0, stream>>>(
        x, ys, xs, W, patches, Wbf, pos);
    gemm_kernel<<<(TOKENS / 128) * (DDIM / 128), 256, 0, stream>>>(
        patches, Wbf, bias, out);
  } else {
    naive_kernel<<<TOKENS, 256, 0, stream>>>(x, ys, xs, W, bias, out);
  }
}

// Round 3
// 89.938 us; speedup vs baseline: 1.0773x; 1.0342x over previous
//
#include <hip/hip_runtime.h>
#include <hip/hip_bf16.h>

// ---- problem constants ----
#define B_IMG   128
#define CH      3
#define HW      224
#define NPATCH  196          // tokens per image
#define TOKENS  25088        // B_IMG * NPATCH
#define PATCH   16
#define FDIM    768          // C*P*P (K of the GEMM)
#define DDIM    768          // output embed dim (N of the GEMM)
#define TOKELEMS ((size_t)TOKENS * FDIM)
#define OUT_TOKENS ((size_t)TOKENS * DDIM)     // positions follow in d_out

#define GATHER_BLOCKS (TOKENS * (FDIM / 4) / 256)   // 18816
#define WCONV_BLOCKS  ((DDIM * FDIM / 4) / 256)     // 576

typedef short short8 __attribute__((ext_vector_type(8)));
typedef float f32x4  __attribute__((ext_vector_type(4)));

static __device__ __forceinline__ unsigned short f2bf(float v) {
  unsigned u = __float_as_uint(v);
  unsigned r = u + 0x7fffu + ((u >> 16) & 1u);
  return (unsigned short)(r >> 16);
}

static __device__ __forceinline__ void gload16(const short* g, short* l) {
  __builtin_amdgcn_global_load_lds(
      (const __attribute__((address_space(1))) void*)g,
      (__attribute__((address_space(3))) void*)l,
      16, 0, 0);
}

// ---- kernel 1: gather patches -> bf16 [TOKENS][768] + positions, W -> bf16 ----
__global__ __launch_bounds__(256) void prep_kernel(
    const float* __restrict__ x, const int* __restrict__ ys,
    const int* __restrict__ xs, const float* __restrict__ W,
    short* __restrict__ patches, short* __restrict__ Wbf,
    float* __restrict__ pos) {
  const int blk = blockIdx.x;
  if (blk < GATHER_BLOCKS) {
    int e   = blk * 256 + threadIdx.x;      // quad index
    int tok = e / 192;
    int q   = e - tok * 192;
    int f   = q * 4;
    int b   = tok / NPATCH;
    int y   = ys[tok];
    int xc  = xs[tok];
    int c   = f >> 8;
    int rem = f & 255;
    int py  = rem >> 4;
    int px  = rem & 15;
    const float* src = x + ((size_t)(b * CH + c) * HW + (y + py)) * HW + xc + px;
    ushort4 o;
    o.x = f2bf(src[0]); o.y = f2bf(src[1]); o.z = f2bf(src[2]); o.w = f2bf(src[3]);
    *(ushort4*)&patches[(size_t)tok * FDIM + f] = o;
    if (q == 0) {
      pos[(size_t)tok * 2]     = (float)y;
      pos[(size_t)tok * 2 + 1] = (float)xc;
    }
  } else {
    int i = ((blk - GATHER_BLOCKS) * 256 + threadIdx.x) * 4;
    float4 v = *(const float4*)&W[i];
    ushort4 o;
    o.x = f2bf(v.x); o.y = f2bf(v.y); o.z = f2bf(v.z); o.w = f2bf(v.w);
    *(ushort4*)&Wbf[i] = o;
  }
}

// ---- kernel 2: bf16 MFMA GEMM, 128x128 tile, ring-4 counted-vmcnt pipeline ----
// C[m][d] = sum_f A[m][f] * Wbf[d][f] + bias[d]
// T4: stage K-tile t+3 each iter, s_waitcnt vmcnt(12) (never 0 in main loop),
// RAW s_barrier (NOT __syncthreads — that drains vmcnt(0) and kills the pipe).
__global__ __launch_bounds__(256) void gemm_kernel(
    const short* __restrict__ A,    // patches bf16 [TOKENS][768]
    const short* __restrict__ Bw,   // Wbf bf16 [768][768]
    const float* __restrict__ bias,
    float* __restrict__ C) {
  __shared__ short At[4][128 * 32];   // 4-deep ring, 8KB per buffer
  __shared__ short Bt[4][128 * 32];   // total LDS 64KB -> 2 blocks/CU

  const int tid  = threadIdx.x;
  const int w    = tid >> 6;
  const int l    = tid & 63;

  // bijective XCD swizzle: nwg = 1176 = 8 * 147 (groups the 6 N-tiles of an
  // M row-panel on one XCD's L2; R2 measured FETCH 118->34.6 MB).
  const int id  = blockIdx.x;
  const int nid = (id & 7) * 147 + (id >> 3);
  const int m0  = (nid / 6) * 128;
  const int n0  = (nid % 6) * 128;

  const int wrow = w >> 1;
  const int wcol = w & 1;
  const int lr   = l & 15;
  const int lg   = l >> 4;

  f32x4 acc[4][4];
  const f32x4 z = {0.f, 0.f, 0.f, 0.f};
#pragma unroll
  for (int mi = 0; mi < 4; ++mi)
#pragma unroll
    for (int ni = 0; ni < 4; ++ni) acc[mi][ni] = z;

  // Pin the 4 bias loads COMPLETE before any staging: they must not sit in
  // the vmcnt queue or the counted waits below miscount.
  float bs[4];
#pragma unroll
  for (int ni = 0; ni < 4; ++ni)
    bs[ni] = bias[n0 + wcol * 64 + ni * 16 + lr];
#pragma unroll
  for (int ni = 0; ni < 4; ++ni) asm volatile("" : "+v"(bs[ni]));

  // each wave stages its 32 rows per operand (2 x gload16 of 16 rows each)
  const int rw = w * 32;
  const short* gA = A + (size_t)(m0 + rw + (l >> 2)) * FDIM + ((l & 3) << 3);
  const short* gB = Bw + (size_t)(n0 + rw + (l >> 2)) * FDIM + ((l & 3) << 3);

  auto stage = [&](int buf, int kt) {
    const int ko = kt * 32;
    short* lA = &At[buf][rw * 32];
    short* lB = &Bt[buf][rw * 32];
    gload16(gA + ko, lA);
    gload16(gA + 16 * FDIM + ko, lA + 16 * 32);
    gload16(gB + ko, lB);
    gload16(gB + 16 * FDIM + ko, lB + 16 * 32);
  };
  auto compute = [&](int buf) {
    const short* Ab = At[buf];
    const short* Bb = Bt[buf];
    short8 a[4], b[4];
    const int koff = lg * 8;
#pragma unroll
    for (int mi = 0; mi < 4; ++mi)
      a[mi] = *(const short8*)&Ab[(wrow * 64 + mi * 16 + lr) * 32 + koff];
#pragma unroll
    for (int ni = 0; ni < 4; ++ni)
      b[ni] = *(const short8*)&Bb[(wcol * 64 + ni * 16 + lr) * 32 + koff];
    __builtin_amdgcn_s_setprio(1);
#pragma unroll
    for (int mi = 0; mi < 4; ++mi)
#pragma unroll
      for (int ni = 0; ni < 4; ++ni)
        acc[mi][ni] =
            __builtin_amdgcn_mfma_f32_16x16x32_bf16(a[mi], b[ni], acc[mi][ni], 0, 0, 0);
    __builtin_amdgcn_s_setprio(0);
  };

  // prologue: 3 tiles in flight (12 loads/wave outstanding)
  stage(0, 0);
  stage(1, 1);
  stage(2, 2);

  // main loop: 21 iters; stage t+3 (16 outstanding), wait back to 12 (= tile t
  // landed), barrier, compute. Loads get ~3 iterations to cover latency.
  for (int t = 0; t < 21; ++t) {
    stage((t + 3) & 3, t + 3);
    asm volatile("s_waitcnt vmcnt(12)" ::: "memory");
    __builtin_amdgcn_s_barrier();
    compute(t & 3);
    __builtin_amdgcn_s_barrier();
  }
  // epilogue drain: 12 -> 8 -> 4 -> 0
  asm volatile("s_waitcnt vmcnt(8)" ::: "memory");
  __builtin_amdgcn_s_barrier();
  compute(21 & 3);
  __builtin_amdgcn_s_barrier();
  asm volatile("s_waitcnt vmcnt(4)" ::: "memory");
  __builtin_amdgcn_s_barrier();
  compute(22 & 3);
  __builtin_amdgcn_s_barrier();
  asm volatile("s_waitcnt vmcnt(0)" ::: "memory");
  __builtin_amdgcn_s_barrier();
  compute(23 & 3);

  // epilogue: C/D layout col = lane&15, row = (lane>>4)*4 + j
#pragma unroll
  for (int ni = 0; ni < 4; ++ni) {
    const int col = n0 + wcol * 64 + ni * 16 + lr;
#pragma unroll
    for (int mi = 0; mi < 4; ++mi) {
      const int row = m0 + wrow * 64 + mi * 16 + lg * 4;
      const f32x4 v = acc[mi][ni];
#pragma unroll
      for (int j = 0; j < 4; ++j)
        C[(size_t)(row + j) * DDIM + col] = v[j] + bs[ni];
    }
  }
}

// ---- fallback (ws too small): naive fused f32, correct but slow ----
__global__ __launch_bounds__(256) void naive_kernel(
    const float* __restrict__ x, const int* __restrict__ ys,
    const int* __restrict__ xs, const float* __restrict__ W,
    const float* __restrict__ bias, float* __restrict__ out) {
  __shared__ float prow[FDIM];
  const int tok = blockIdx.x;
  const int t   = threadIdx.x;
  const int b   = tok / NPATCH;
  const int y   = ys[tok];
  const int xc  = xs[tok];
  for (int i = t; i < FDIM; i += 256) {
    int c = i >> 8, rem = i & 255, py = rem >> 4, px = rem & 15;
    prow[i] = x[((size_t)(b * CH + c) * HW + y + py) * HW + xc + px];
  }
  __syncthreads();
  for (int dd = 0; dd < 3; ++dd) {
    const int d = t + dd * 256;
    float s = bias[d];
    const float4* wr = (const float4*)&W[(size_t)d * FDIM];
    const float4* pr = (const float4*)prow;
    for (int f4 = 0; f4 < FDIM / 4; ++f4) {
      float4 wv = wr[f4];
      float4 pv = pr[f4];
      s += wv.x * pv.x + wv.y * pv.y + wv.z * pv.z + wv.w * pv.w;
    }
    out[(size_t)tok * DDIM + d] = s;
  }
  if (t == 0) {
    float* pos = out + OUT_TOKENS;
    pos[(size_t)tok * 2]     = (float)y;
    pos[(size_t)tok * 2 + 1] = (float)xc;
  }
}

extern "C" void kernel_launch(void* const* d_in, const int* in_sizes, int n_in,
                              void* d_out, int out_size, void* d_ws, size_t ws_size,
                              hipStream_t stream) {
  const float* x    = (const float*)d_in[0];
  const int*   ys   = (const int*)d_in[1];
  const int*   xs   = (const int*)d_in[2];
  const float* W    = (const float*)d_in[3];
  const float* bias = (const float*)d_in[4];
  float* out = (float*)d_out;
  float* pos = out + OUT_TOKENS;

  const size_t w_bytes = (size_t)DDIM * FDIM * 2;
  const size_t p_bytes = TOKELEMS * 2;
  if (ws_size >= w_bytes + p_bytes) {
    short* Wbf     = (short*)d_ws;
    short* patches = (short*)d_ws + (size_t)DDIM * FDIM;
    prep_kernel<<<GATHER_BLOCKS + WCONV_BLOCKS, 256, 0, stream>>>(
        x, ys, xs, W, patches, Wbf, pos);
    gemm_kernel<<<(TOKENS / 128) * (DDIM / 128), 256, 0, stream>>>(
        patches, Wbf, bias, out);
  } else {
    naive_kernel<<<TOKENS, 256, 0, stream>>>(x, ys, xs, W, bias, out);
  }
}